// Round 4
// baseline (113.161 us; speedup 1.0000x reference)
//
#include <hip/hip_runtime.h>

#define BATCH 64
#define N_IN  2048
#define NN    512
#define KR    8            // k-ranges (256 rows each)
#define ALPHA 0.995f
#define BETA  0.975f
#define V_TH  2.0f

// ---------------- K1: drive1 partials, pure contiguous streaming ----------------
// block = (kr, b): streams x[b, kr*256:(kr+1)*256, 0:512]  (contiguous 512 KB)
// thread: c4 = tid&127 (float4 col), kl = tid>>7 (k row mod 8)
__global__ __launch_bounds__(1024, 8)
void k1_drive1(const float* __restrict__ x,
               const float* __restrict__ w,
               float* __restrict__ ws)
{
    const int kr  = blockIdx.x;          // 0..7  (id%8 -> same kr per XCD)
    const int b   = blockIdx.y;          // 0..63
    const int tid = threadIdx.x;
    const int c4  = tid & 127;           // float4 column 0..127  (n = 4*c4..)
    const int kl  = tid >> 7;            // 0..7

    const float4* __restrict__ x4 = (const float4*)x;
    const float4* __restrict__ w4 = (const float4*)w;

    const float4* xp = x4 + ((size_t)b * N_IN + kr * 256 + kl) * 128 + c4;
    const float4* wp = w4 + ((size_t)(kr * 256 + kl)) * 128 + c4;
    const size_t  ks = 8 * 128;          // 8 k-rows in float4 units

    float4 acc = make_float4(0.f, 0.f, 0.f, 0.f);
#pragma unroll
    for (int i = 0; i < 8; ++i) {        // 8 batches x 4 k-steps = 32 k rows
        float4 xv[4], wv[4];
#pragma unroll
        for (int u = 0; u < 4; ++u) xv[u] = xp[u * ks];   // HBM stream first
#pragma unroll
        for (int u = 0; u < 4; ++u) wv[u] = wp[u * ks];   // L2-hot second
#pragma unroll
        for (int u = 0; u < 4; ++u) {
            acc.x += xv[u].x * wv[u].x;
            acc.y += xv[u].y * wv[u].y;
            acc.z += xv[u].z * wv[u].z;
            acc.w += xv[u].w * wv[u].w;
        }
        xp += 4 * ks;
        wp += 4 * ks;
    }

    __shared__ float4 red[1024];         // 16 KB
    red[tid] = acc;
    __syncthreads();
    if (tid < 128) {                     // c4 == tid here
        float4 s = red[tid];
#pragma unroll
        for (int g = 1; g < 8; ++g) {
            const float4 o = red[tid + 128 * g];
            s.x += o.x; s.y += o.y; s.z += o.z; s.w += o.w;
        }
        ((float4*)ws)[((size_t)kr * BATCH + b) * 128 + tid] = s;
    }
}

// ---------------- K2: partial-sum + LOO recurrent drive + epilogue ----------------
// block = b (64 blocks, 1024 threads): thread = (n = tid&511, jh = tid>>9)
__global__ __launch_bounds__(1024)
void k2_finish(const float* __restrict__ v,
               const float* __restrict__ z,
               const float* __restrict__ z_out,
               const float* __restrict__ w,
               const float* __restrict__ ws,
               float* __restrict__ out)
{
    const int b   = blockIdx.x;
    const int tid = threadIdx.x;
    const int n   = tid & 511;
    const int jh  = tid >> 9;            // 0..1

    __shared__ float zlds[NN];
    __shared__ float r2[1024];

    if (tid < NN)
        zlds[tid] = BETA * z_out[b * NN + tid] + z[b * NN + tid];
    __syncthreads();

    // drive2 = sum_j zlds[j + (j>=n)] * w[N_IN + j, n]
    float d2 = 0.f;
    for (int j = jh; j < NN - 1; j += 2)
        d2 += zlds[j + (j >= n)] * w[(size_t)(N_IN + j) * NN + n];
    r2[tid] = d2;
    __syncthreads();

    if (tid < NN) {
        float d1 = 0.f;
#pragma unroll
        for (int kr = 0; kr < KR; ++kr)
            d1 += ws[((size_t)kr * BATCH + b) * NN + n];
        const float d2s   = r2[n] + r2[n + 512];
        const float vv    = v[b * NN + n];
        const float zz    = z[b * NN + n];
        const float v_new = ALPHA * vv + d1 + d2s - V_TH * zz;
        out[b * NN + n]                  = v_new;
        out[BATCH * NN + b * NN + n]     = (v_new - V_TH > 0.f) ? 1.f : 0.f;
        out[2 * BATCH * NN + b * NN + n] = zlds[n];
    }
}

extern "C" void kernel_launch(void* const* d_in, const int* in_sizes, int n_in,
                              void* d_out, int out_size, void* d_ws, size_t ws_size,
                              hipStream_t stream) {
    (void)in_sizes; (void)n_in; (void)out_size; (void)ws_size;
    const float* x     = (const float*)d_in[0];
    const float* v     = (const float*)d_in[1];
    const float* z     = (const float*)d_in[2];
    const float* z_out = (const float*)d_in[3];
    const float* w     = (const float*)d_in[4];
    float* out = (float*)d_out;
    float* ws  = (float*)d_ws;           // 8*64*512 floats = 1 MB

    dim3 g1(KR, BATCH);                  // 512 blocks, 2/CU, 32 waves/CU
    k1_drive1<<<g1, 1024, 0, stream>>>(x, w, ws);
    k2_finish<<<BATCH, 1024, 0, stream>>>(v, z, z_out, w, ws, out);
}

// Round 5
// 100.064 us; speedup vs baseline: 1.1309x; 1.1309x over previous
//
#include <hip/hip_runtime.h>

#define BATCH 64
#define N_IN  2048
#define NN    512
#define NCH   16          // n columns per block
#define G     4           // batches per block (w amortization factor)
#define THREADS 1024
#define ALPHA 0.995f
#define BETA  0.975f
#define V_TH  2.0f

__global__ __launch_bounds__(THREADS, 8)   // cap VGPR<=64: 2 blocks/CU, 32 waves/CU
void fused_step(const float* __restrict__ x,
                const float* __restrict__ v,
                const float* __restrict__ z,
                const float* __restrict__ z_out,
                const float* __restrict__ w,
                float* __restrict__ out)
{
    const int nc   = blockIdx.x;        // 0..31  (id%8 -> nc%8 per XCD: w slices L2-hot)
    const int bq   = blockIdx.y;        // 0..15
    const int b0   = bq * G;
    const int nb   = nc * NCH;
    const int tid  = threadIdx.x;
    const int nl   = tid & 3;           // float4 col within the 16-col chunk
    const int kk   = tid >> 2;          // 0..255
    const int wid  = tid >> 6;
    const int lane = tid & 63;

    __shared__ float  zlds[G][NN];        // z_out_new, 4 batches (8 KB)
    __shared__ float4 wpart[16][G][4];    // per-wave drive1 partials (4 KB)
    __shared__ float  d1s[G][NCH];        // final drive1 (256 B)
    __shared__ float  red2[THREADS];      // drive2 partials (4 KB)

    // ---- z_out_new = BETA * z_out + z  (full rows for the LOO gather)
    for (int i = tid; i < G * NN; i += THREADS) {
        const int g = i >> 9, idx = i & 511;
        zlds[g][idx] = BETA * z_out[(b0 + g) * NN + idx] + z[(b0 + g) * NN + idx];
    }

    // ---- drive1: w loaded ONCE per k-row, reused across G batches
    const float4* __restrict__ x4 = (const float4*)x;
    const float4* __restrict__ w4 = (const float4*)w;
    const int c4 = (nb >> 2) + nl;        // float4 column in the 128-wide row

    float4 acc[G];
#pragma unroll
    for (int g = 0; g < G; ++g) acc[g] = make_float4(0.f, 0.f, 0.f, 0.f);

#pragma unroll 2
    for (int i = 0; i < 8; ++i) {         // k = kk + 256*i
        const size_t roff = (size_t)(kk + 256 * i) * 128 + c4;
        float4 xv[G];
#pragma unroll
        for (int g = 0; g < G; ++g)       // HBM streams first
            xv[g] = x4[(size_t)(b0 + g) * (N_IN * 128) + roff];
        const float4 wv = w4[roff];       // L2-hot second
#pragma unroll
        for (int g = 0; g < G; ++g) {
            acc[g].x += xv[g].x * wv.x;
            acc[g].y += xv[g].y * wv.y;
            acc[g].z += xv[g].z * wv.z;
            acc[g].w += xv[g].w * wv.w;
        }
    }

    // ---- in-wave reduce over the 16 kk-groups sharing this wave (same nl)
#pragma unroll
    for (int off = 32; off >= 4; off >>= 1) {
#pragma unroll
        for (int g = 0; g < G; ++g) {
            acc[g].x += __shfl_down(acc[g].x, off);
            acc[g].y += __shfl_down(acc[g].y, off);
            acc[g].z += __shfl_down(acc[g].z, off);
            acc[g].w += __shfl_down(acc[g].w, off);
        }
    }
    if (lane < 4) {
#pragma unroll
        for (int g = 0; g < G; ++g) wpart[wid][g][lane] = acc[g];
    }
    __syncthreads();   // covers zlds + wpart

    // ---- final drive1 column sums (threads 0..15, overlaps drive2 on others)
    if (tid < 16) {
        const int g = tid >> 2, c = tid & 3;
        float4 s = wpart[0][g][c];
#pragma unroll
        for (int ww = 1; ww < 16; ++ww) {
            const float4 o = wpart[ww][g][c];
            s.x += o.x; s.y += o.y; s.z += o.z; s.w += o.w;
        }
        d1s[g][c * 4 + 0] = s.x;
        d1s[g][c * 4 + 1] = s.y;
        d1s[g][c * 4 + 2] = s.z;
        d1s[g][c * 4 + 3] = s.w;
    }

    // ---- drive2 = sum_j zlds[g][j+(j>=n)] * w[N_IN+j, n]
    {
        const int g     = tid >> 8;          // 0..3
        const int rem   = tid & 255;
        const int jg    = rem >> 4;          // 0..15
        const int n_loc = rem & 15;
        const int n     = nb + n_loc;
        float d2 = 0.f;
        for (int j = jg; j < NN - 1; j += 16)
            d2 += zlds[g][j + (j >= n)] * w[(size_t)(N_IN + j) * NN + n];
        red2[tid] = d2;
    }
    __syncthreads();

    // ---- epilogue
    if (tid < 64) {
        const int g     = tid >> 4;
        const int n_loc = tid & 15;
        const int n     = nb + n_loc;
        float d2s = 0.f;
#pragma unroll
        for (int jg = 0; jg < 16; ++jg) d2s += red2[g * 256 + jg * 16 + n_loc];
        const float vv    = v[(b0 + g) * NN + n];
        const float zz    = z[(b0 + g) * NN + n];
        const float v_new = ALPHA * vv + d1s[g][n_loc] + d2s - V_TH * zz;
        out[(b0 + g) * NN + n]                  = v_new;
        out[BATCH * NN + (b0 + g) * NN + n]     = (v_new - V_TH > 0.f) ? 1.f : 0.f;
        out[2 * BATCH * NN + (b0 + g) * NN + n] = zlds[g][n];
    }
}

extern "C" void kernel_launch(void* const* d_in, const int* in_sizes, int n_in,
                              void* d_out, int out_size, void* d_ws, size_t ws_size,
                              hipStream_t stream) {
    (void)in_sizes; (void)n_in; (void)out_size; (void)d_ws; (void)ws_size;
    const float* x     = (const float*)d_in[0];
    const float* v     = (const float*)d_in[1];
    const float* z     = (const float*)d_in[2];
    const float* z_out = (const float*)d_in[3];
    const float* w     = (const float*)d_in[4];
    float* out = (float*)d_out;

    dim3 grid(NN / NCH, BATCH / G);   // 32 x 16 = 512 blocks, 2/CU, 32 waves/CU
    fused_step<<<grid, THREADS, 0, stream>>>(x, v, z, z_out, w, out);
}

// Round 6
// 62.390 us; speedup vs baseline: 1.8138x; 1.6038x over previous
//
#include <hip/hip_runtime.h>

#define BATCH 64
#define N_IN  2048
#define NN    512
#define KR    8            // k-ranges (256 rows each)
#define ALPHA 0.995f
#define BETA  0.975f
#define V_TH  2.0f

// ---------------- K1: drive1 partials, pure contiguous streaming ----------------
// block = (kr, b): streams x[b, kr*256:(kr+1)*256, 0:512]  (contiguous 512 KB)
// wave-load = 64 lanes x float4 = 1 KB single contiguous segment.
// blockid%8 == kr -> each XCD keeps ONE 512 KB w-slab L2-resident.
__global__ __launch_bounds__(1024, 8)
void k1_drive1(const float* __restrict__ x,
               const float* __restrict__ w,
               float* __restrict__ ws)
{
    const int kr  = blockIdx.x;          // 0..7
    const int b   = blockIdx.y;          // 0..63
    const int tid = threadIdx.x;
    const int c4  = tid & 127;           // float4 column 0..127
    const int kl  = tid >> 7;            // 0..7

    const float4* __restrict__ x4 = (const float4*)x;
    const float4* __restrict__ w4 = (const float4*)w;

    const float4* xp = x4 + ((size_t)b * N_IN + kr * 256 + kl) * 128 + c4;
    const float4* wp = w4 + ((size_t)(kr * 256 + kl)) * 128 + c4;
    const size_t  ks = 8 * 128;          // 8 k-rows in float4 units

    float4 acc = make_float4(0.f, 0.f, 0.f, 0.f);
#pragma unroll
    for (int i = 0; i < 8; ++i) {        // 8 batches x 4 k-steps = 32 k rows
        float4 xv[4], wv[4];
#pragma unroll
        for (int u = 0; u < 4; ++u) xv[u] = xp[u * ks];   // HBM stream first
#pragma unroll
        for (int u = 0; u < 4; ++u) wv[u] = wp[u * ks];   // L2-hot second
#pragma unroll
        for (int u = 0; u < 4; ++u) {
            acc.x += xv[u].x * wv[u].x;
            acc.y += xv[u].y * wv[u].y;
            acc.z += xv[u].z * wv[u].z;
            acc.w += xv[u].w * wv[u].w;
        }
        xp += 4 * ks;
        wp += 4 * ks;
    }

    __shared__ float4 red[1024];         // 16 KB
    red[tid] = acc;
    __syncthreads();
    if (tid < 128) {                     // c4 == tid here
        float4 s = red[tid];
#pragma unroll
        for (int g = 1; g < 8; ++g) {
            const float4 o = red[tid + 128 * g];
            s.x += o.x; s.y += o.y; s.z += o.z; s.w += o.w;
        }
        ((float4*)ws)[((size_t)kr * BATCH + b) * 128 + tid] = s;
    }
}

// ---------------- K2: partial-sum + LOO recurrent drive + epilogue ----------------
// 512 blocks = (nc 0..7) x (b 0..63), 1024 threads. Each block owns 64 n-columns.
// blockid%8 == nc -> per-XCD w2 column slice (128 KB) L2-resident.
__global__ __launch_bounds__(1024)
void k2_finish(const float* __restrict__ v,
               const float* __restrict__ z,
               const float* __restrict__ z_out,
               const float* __restrict__ w,
               const float* __restrict__ ws,
               float* __restrict__ out)
{
    const int nc  = blockIdx.x;          // 0..7
    const int b   = blockIdx.y;          // 0..63
    const int nb  = nc * 64;
    const int tid = threadIdx.x;

    __shared__ float zlds[NN];
    __shared__ float r2[1024];

    if (tid < NN)
        zlds[tid] = BETA * z_out[b * NN + tid] + z[b * NN + tid];
    __syncthreads();

    // drive2 = sum_j zlds[j + (j>=n)] * w[N_IN + j, n], 16-way j-interleave
    const int n_loc = tid & 63;
    const int n     = nb + n_loc;
    const int jg    = tid >> 6;          // 0..15
    float d2 = 0.f;
#pragma unroll 4
    for (int j = jg; j < NN - 1; j += 16)
        d2 += zlds[j + (j >= n)] * w[(size_t)(N_IN + j) * NN + n];
    r2[tid] = d2;
    __syncthreads();

    if (tid < 64) {
        float d1 = 0.f;
#pragma unroll
        for (int kr = 0; kr < KR; ++kr)
            d1 += ws[((size_t)kr * BATCH + b) * NN + n];
        float d2s = 0.f;
#pragma unroll
        for (int g = 0; g < 16; ++g) d2s += r2[g * 64 + n_loc];
        const float vv    = v[b * NN + n];
        const float zz    = z[b * NN + n];
        const float v_new = ALPHA * vv + d1 + d2s - V_TH * zz;
        out[b * NN + n]                  = v_new;
        out[BATCH * NN + b * NN + n]     = (v_new - V_TH > 0.f) ? 1.f : 0.f;
        out[2 * BATCH * NN + b * NN + n] = zlds[n];
    }
}

extern "C" void kernel_launch(void* const* d_in, const int* in_sizes, int n_in,
                              void* d_out, int out_size, void* d_ws, size_t ws_size,
                              hipStream_t stream) {
    (void)in_sizes; (void)n_in; (void)out_size; (void)ws_size;
    const float* x     = (const float*)d_in[0];
    const float* v     = (const float*)d_in[1];
    const float* z     = (const float*)d_in[2];
    const float* z_out = (const float*)d_in[3];
    const float* w     = (const float*)d_in[4];
    float* out = (float*)d_out;
    float* ws  = (float*)d_ws;           // 8*64*512 floats = 1 MB

    dim3 g1(KR, BATCH);                  // 512 blocks, 2/CU, 32 waves/CU
    k1_drive1<<<g1, 1024, 0, stream>>>(x, w, ws);
    dim3 g2(KR, BATCH);                  // 512 blocks
    k2_finish<<<g2, 1024, 0, stream>>>(v, z, z_out, w, ws, out);
}